// Round 1
// 417.389 us; speedup vs baseline: 1.0709x; 1.0709x over previous
//
#include <hip/hip_runtime.h>

// Causal single-head attention, B=8, N=2048, D=1024, fp32 in/out, bf16 MFMA compute.
//
// Pipeline (all on `stream`):
//   1. cast_f32_bf16:      x (fp32) -> xb (bf16)
//   2. transpose_cast_w:   Wq/Wk/Wv (fp32 KxN) -> WT (bf16 NxK)
//   3. gemm256<0>: Q = xb·Wq; K = xb·Wk; gemm256<1>: Vt = (xb·Wv)^T
//   4. gemm256<2>: E = exp(scale·Q·K^T) bf16, causal-masked, lower 256x256 tiles only.
//   5. gemm_bt<3>: out = (E·V)/rowsum(E)  (old 128x128 structure, heavy-first order)
//
// gemm256: 256x256 tile, 512 thr (8 waves = 2M x 4N), BK=32, 4-deep LDS ring with
// counted vmcnt (T3+T4: loads stay in flight across raw s_barriers, never drained to 0
// in steady state), XOR-swizzled LDS reads via pre-swizzled global source (T2, rule 21),
// setprio around the MFMA cluster (T5).

typedef unsigned short u16;
typedef __bf16 bf16x8 __attribute__((ext_vector_type(8)));
typedef float f32x4 __attribute__((ext_vector_type(4)));
typedef unsigned short u16x8 __attribute__((ext_vector_type(8)));
typedef unsigned short u16x4 __attribute__((ext_vector_type(4)));

static constexpr int BATCH = 8;
static constexpr int SEQ = 2048;
static constexpr int DIM = 1024;

static constexpr size_t SZ_XB = (size_t)BATCH * SEQ * DIM * 2;  // 32 MiB
static constexpr size_t SZ_W  = (size_t)DIM * DIM * 2;          // 2 MiB
static constexpr size_t OFF_XB  = 0;
static constexpr size_t OFF_WQT = OFF_XB + SZ_XB;
static constexpr size_t OFF_WKT = OFF_WQT + SZ_W;
static constexpr size_t OFF_WVT = OFF_WKT + SZ_W;
static constexpr size_t OFF_Q   = OFF_WVT + SZ_W;
static constexpr size_t OFF_K   = OFF_Q + SZ_XB;
static constexpr size_t OFF_VT  = OFF_K + SZ_XB;
static constexpr size_t OFF_E   = OFF_VT + SZ_XB;  // bf16 8x2048x2048 = 64 MiB
// total ~198 MiB

__device__ __forceinline__ u16 f2b(float f) {
  unsigned u = __builtin_bit_cast(unsigned, f);
  u += 0x7fffu + ((u >> 16) & 1u);
  return (u16)(u >> 16);
}

__device__ __forceinline__ void gload16(const u16* g, u16* l) {
  __builtin_amdgcn_global_load_lds((__attribute__((address_space(1))) void*)g,
                                   (__attribute__((address_space(3))) void*)l, 16, 0, 0);
}

#define VWAIT(N) asm volatile("s_waitcnt vmcnt(" #N ")" ::: "memory")

__device__ __forceinline__ void barrier_raw() {
  __builtin_amdgcn_sched_barrier(0);
  __builtin_amdgcn_s_barrier();
  __builtin_amdgcn_sched_barrier(0);
}

__global__ __launch_bounds__(256) void cast_f32_bf16(const float* __restrict__ in,
                                                     u16* __restrict__ out) {
  const size_t i = ((size_t)blockIdx.x * 256 + threadIdx.x) * 8;
  float4 a = *(const float4*)(in + i);
  float4 b = *(const float4*)(in + i + 4);
  u16x8 o;
  o[0] = f2b(a.x); o[1] = f2b(a.y); o[2] = f2b(a.z); o[3] = f2b(a.w);
  o[4] = f2b(b.x); o[5] = f2b(b.y); o[6] = f2b(b.z); o[7] = f2b(b.w);
  *reinterpret_cast<u16x8*>(out + i) = o;
}

__global__ __launch_bounds__(256) void transpose_cast_w(const float* __restrict__ W,
                                                        u16* __restrict__ WT) {
  __shared__ float t[32][33];
  const int k0 = blockIdx.x * 32, n0 = blockIdx.y * 32;
  const int tx = threadIdx.x, ty = threadIdx.y;
#pragma unroll
  for (int dy = 0; dy < 32; dy += 8)
    t[ty + dy][tx] = W[(size_t)(k0 + ty + dy) * DIM + n0 + tx];
  __syncthreads();
#pragma unroll
  for (int dy = 0; dy < 32; dy += 8)
    WT[(size_t)(n0 + ty + dy) * DIM + k0 + tx] = f2b(t[tx][ty + dy]);
}

// ---------------------------------------------------------------------------
// gemm256<MODE>: C = A(bf16 MxK rm) * Bt(bf16 NxK rm)^T, 256x256 tile.
// MODE 0: C bf16 row-major
// MODE 1: C bf16 transposed per batch: C[b][col][n], b=row>>11, n=row&2047 (Vt build)
// MODE 2: C bf16 = exp(acc*scale) causal-masked; lower-triangular tiles only (bx<=by)
//
// LDS swizzle: logical A[256][32] bf16 (64B rows). Read of (row, quad) is 16B at
//   byte ((row*64 + quad*16) ^ (((row>>1)&7)<<4)).
// global_load_lds writes linearly (chunk c -> byte c*16), so the per-lane GLOBAL
// source for chunk c is the inverse image:  P=c>>3, u=(c&7)^(P&7),
//   row = 2P + (u>>2), kchunk = u&3.   (Verified: swz(row,kchunk) == c*16.)
// Result: lanes 0..15 of a b128 frag read hit each bank-slot at most 2x (free).
// ---------------------------------------------------------------------------
template <int MODE>
__global__ __launch_bounds__(512, 2) void gemm256(
    const u16* __restrict__ A, size_t sA, int lda,
    const u16* __restrict__ Bt, size_t sB, int ldb,
    void* __restrict__ C, size_t sC, int ldc,
    int Kdim, float scale) {
  const int bx = blockIdx.x, by = blockIdx.y, bz = blockIdx.z;
  if (MODE == 2 && bx > by) return;
  const u16* Ab = A + (size_t)bz * sA;
  const u16* Bb = Bt + (size_t)bz * sB;
  const int rowTile = by * 256, colTile = bx * 256;
  const int NT = Kdim >> 5;  // BK=32

  __shared__ __align__(16) u16 lds[4 * 16384];  // 4 stages x (A 16KB + B 16KB) = 128 KiB

  const int tid = threadIdx.x;
  const int w = tid >> 6, l = tid & 63;
  const int wm = w >> 2, wn = w & 3;  // 2 x 4 wave grid; wave owns 128x64 of C
  const int lr = l & 15, quad = l >> 4;

  // staging source pointers (inverse swizzle), chunks c = tid and tid+512
  auto srow = [](int c) { int u = (c & 7) ^ ((c >> 3) & 7); return 2 * (c >> 3) + (u >> 2); };
  auto skq  = [](int c) { int u = (c & 7) ^ ((c >> 3) & 7); return u & 3; };
  const u16* pA0 = Ab + (size_t)(rowTile + srow(tid)) * lda + skq(tid) * 8;
  const u16* pA1 = Ab + (size_t)(rowTile + srow(tid + 512)) * lda + skq(tid + 512) * 8;
  const u16* pB0 = Bb + (size_t)(colTile + srow(tid)) * ldb + skq(tid) * 8;
  const u16* pB1 = Bb + (size_t)(colTile + srow(tid + 512)) * ldb + skq(tid + 512) * 8;

  // swizzled LDS read offsets (u16 units, 16B aligned)
  int offA[8], offB[4];
#pragma unroll
  for (int mi = 0; mi < 8; ++mi) {
    const int row = wm * 128 + mi * 16 + lr;
    offA[mi] = ((row * 64 + quad * 16) ^ (((row >> 1) & 7) << 4)) >> 1;
  }
#pragma unroll
  for (int ni = 0; ni < 4; ++ni) {
    const int row = wn * 64 + ni * 16 + lr;
    offB[ni] = ((row * 64 + quad * 16) ^ (((row >> 1) & 7) << 4)) >> 1;
  }

  f32x4 acc[8][4];
#pragma unroll
  for (int i = 0; i < 8; ++i)
#pragma unroll
    for (int j = 0; j < 4; ++j) acc[i][j] = (f32x4){0.f, 0.f, 0.f, 0.f};

#define STAGE256(tt)                              \
  {                                               \
    u16* sb = &lds[((tt) & 3) * 16384];           \
    const int ko = (tt) * 32;                     \
    gload16(pA0 + ko, sb + w * 512);              \
    gload16(pA1 + ko, sb + 4096 + w * 512);       \
    gload16(pB0 + ko, sb + 8192 + w * 512);       \
    gload16(pB1 + ko, sb + 12288 + w * 512);      \
  }

  STAGE256(0);
  STAGE256(1);
  STAGE256(2);

  for (int t = 0; t < NT; ++t) {
    const u16* As = &lds[(t & 3) * 16384];
    const u16* Bs = As + 8192;
    // Stage 3 tiles ahead; wait only for tile t (4 loads/wave/tile -> 12 newer allowed).
    if (t + 3 < NT) {
      STAGE256(t + 3);
      VWAIT(12);
    } else if (t + 2 < NT) {
      VWAIT(8);
    } else if (t + 1 < NT) {
      VWAIT(4);
    } else {
      VWAIT(0);
    }
    barrier_raw();  // all waves' tile-t loads landed
    bf16x8 af[8], bf[4];
#pragma unroll
    for (int mi = 0; mi < 8; ++mi)
      af[mi] = *reinterpret_cast<const bf16x8*>(&As[offA[mi]]);
#pragma unroll
    for (int ni = 0; ni < 4; ++ni)
      bf[ni] = *reinterpret_cast<const bf16x8*>(&Bs[offB[ni]]);
    __builtin_amdgcn_s_setprio(1);
#pragma unroll
    for (int mi = 0; mi < 8; ++mi)
#pragma unroll
      for (int ni = 0; ni < 4; ++ni)
        acc[mi][ni] =
            __builtin_amdgcn_mfma_f32_16x16x32_bf16(af[mi], bf[ni], acc[mi][ni], 0, 0, 0);
    __builtin_amdgcn_s_setprio(0);
    asm volatile("s_waitcnt lgkmcnt(0)" ::: "memory");  // reads retired
    barrier_raw();  // buf (t&3) free: next iter stages tile t+4 into it
  }
#undef STAGE256

  // C/D layout: col = lane&15, row = (lane>>4)*4 + reg  [m89-verified]
  const int orow0 = rowTile + wm * 128 + quad * 4;
  const int ocol0 = colTile + wn * 64 + lr;
#pragma unroll
  for (int mi = 0; mi < 8; ++mi) {
#pragma unroll
    for (int ni = 0; ni < 4; ++ni) {
      const int colg = ocol0 + ni * 16;
      if (MODE == 1) {
        const int rowg0 = orow0 + mi * 16;  // multiple of 4; no 2048-boundary cross
        const int bb = rowg0 >> 11, nn = rowg0 & (SEQ - 1);
        u16x4 pk;
#pragma unroll
        for (int r = 0; r < 4; ++r) pk[r] = f2b(acc[mi][ni][r]);
        *reinterpret_cast<u16x4*>(&((u16*)C)[(size_t)bb * sC + (size_t)colg * ldc + nn]) = pk;
      } else {
#pragma unroll
        for (int r = 0; r < 4; ++r) {
          const int rowg = orow0 + mi * 16 + r;
          const float v = acc[mi][ni][r];
          if (MODE == 0) {
            ((u16*)C)[(size_t)bz * sC + (size_t)rowg * ldc + colg] = f2b(v);
          } else {  // MODE 2
            const float e = (colg <= rowg) ? __expf(v * scale) : 0.f;
            ((u16*)C)[(size_t)bz * sC + (size_t)rowg * ldc + colg] = f2b(e);
          }
        }
      }
    }
  }
}

// ---------------------------------------------------------------------------
// Old 128x128 / 4-wave kernel, kept for MODE 3 (variable causal kmax + rowsum).
// MODE 3: C fp32 = acc / rowsum(A-row); K-loop limited to (by+1)*128; rowsum from
// A-frags. by reversed so the heaviest tiles dispatch first.
// ---------------------------------------------------------------------------
template <int MODE>
__global__ __launch_bounds__(256, 2) void gemm_bt(
    const u16* __restrict__ A, size_t sA, int lda,
    const u16* __restrict__ Bt, size_t sB, int ldb,
    void* __restrict__ C, size_t sC, int ldc,
    int Kdim, float scale) {
  const int bx = blockIdx.x, bz = blockIdx.z;
  const int by = (MODE == 3) ? (int)(gridDim.y - 1 - blockIdx.y) : (int)blockIdx.y;
  if (MODE == 2 && bx > by) return;
  const u16* Ab = A + (size_t)bz * sA;
  const u16* Bb = Bt + (size_t)bz * sB;
  const int rowTile = by * 128, colTile = bx * 128;
  int kmax = Kdim;
  if (MODE == 3) {
    int km = (by + 1) * 128;
    if (km < kmax) kmax = km;
  }

  __shared__ __align__(16) u16 As[128 * 32];
  __shared__ __align__(16) u16 Bs[128 * 32];

  const int tid = threadIdx.x;
  const int w = tid >> 6, l = tid & 63;
  const int wr = (w >> 1) * 64, wc = (w & 1) * 64;
  const int lr = l & 15, quad = l >> 4;

  f32x4 acc[4][4];
#pragma unroll
  for (int i = 0; i < 4; ++i)
#pragma unroll
    for (int j = 0; j < 4; ++j) acc[i][j] = (f32x4){0.f, 0.f, 0.f, 0.f};
  float rsum[4] = {0.f, 0.f, 0.f, 0.f};  // MODE 3: per-lane partial row sums of A

  const int srow = w * 16 + (l >> 2);
  const int scol = (l & 3) * 8;
  const u16* gA0 = Ab + (size_t)(rowTile + srow) * lda + scol;
  const u16* gA1 = gA0 + (size_t)64 * lda;
  const u16* gB0 = Bb + (size_t)(colTile + srow) * ldb + scol;
  const u16* gB1 = gB0 + (size_t)64 * ldb;
  u16* lA0 = &As[(w * 16) * 32];
  u16* lA1 = &As[(64 + w * 16) * 32];
  u16* lB0 = &Bs[(w * 16) * 32];
  u16* lB1 = &Bs[(64 + w * 16) * 32];

  for (int k0 = 0; k0 < kmax; k0 += 32) {
    __syncthreads();
    gload16(gA0 + k0, lA0);
    gload16(gA1 + k0, lA1);
    gload16(gB0 + k0, lB0);
    gload16(gB1 + k0, lB1);
    __syncthreads();
    bf16x8 af[4], bfr[4];
#pragma unroll
    for (int mi = 0; mi < 4; ++mi)
      af[mi] = *reinterpret_cast<const bf16x8*>(&As[(wr + mi * 16 + lr) * 32 + quad * 8]);
#pragma unroll
    for (int ni = 0; ni < 4; ++ni)
      bfr[ni] = *reinterpret_cast<const bf16x8*>(&Bs[(wc + ni * 16 + lr) * 32 + quad * 8]);
    if (MODE == 3) {
#pragma unroll
      for (int mi = 0; mi < 4; ++mi) {
        float s = 0.f;
#pragma unroll
        for (int j = 0; j < 8; ++j) s += (float)af[mi][j];
        rsum[mi] += s;
      }
    }
#pragma unroll
    for (int mi = 0; mi < 4; ++mi)
#pragma unroll
      for (int ni = 0; ni < 4; ++ni)
        acc[mi][ni] =
            __builtin_amdgcn_mfma_f32_16x16x32_bf16(af[mi], bfr[ni], acc[mi][ni], 0, 0, 0);
  }

  if (MODE == 3) {
#pragma unroll
    for (int mi = 0; mi < 4; ++mi) {
      rsum[mi] += __shfl_xor(rsum[mi], 16);
      rsum[mi] += __shfl_xor(rsum[mi], 32);
    }
  }

  const int orow0 = rowTile + wr + quad * 4;
  const int ocol0 = colTile + wc + lr;
#pragma unroll
  for (int mi = 0; mi < 4; ++mi) {
    float linv[4];
    if (MODE == 3) {
#pragma unroll
      for (int r = 0; r < 4; ++r) linv[r] = 1.f / __shfl(rsum[mi], quad * 4 + r);
    }
#pragma unroll
    for (int ni = 0; ni < 4; ++ni) {
      const int colg = ocol0 + ni * 16;
#pragma unroll
      for (int r = 0; r < 4; ++r) {
        const int rowg = orow0 + mi * 16 + r;
        const float v = acc[mi][ni][r];
        if (MODE == 0) {
          ((u16*)C)[(size_t)bz * sC + (size_t)rowg * ldc + colg] = f2b(v);
        } else if (MODE == 1) {
          const int bb = rowg >> 11, nn = rowg & (SEQ - 1);
          ((u16*)C)[(size_t)bb * sC + (size_t)colg * ldc + nn] = f2b(v);
        } else if (MODE == 2) {
          const float e = (colg <= rowg) ? __expf(v * scale) : 0.f;
          ((u16*)C)[(size_t)bz * sC + (size_t)rowg * ldc + colg] = f2b(e);
        } else {
          ((float*)C)[(size_t)bz * sC + (size_t)rowg * ldc + colg] = v * linv[r];
        }
      }
    }
  }
}

extern "C" void kernel_launch(void* const* d_in, const int* in_sizes, int n_in,
                              void* d_out, int out_size, void* d_ws, size_t ws_size,
                              hipStream_t stream) {
  const float* x = (const float*)d_in[0];
  const float* Wq = (const float*)d_in[1];
  const float* Wk = (const float*)d_in[2];
  const float* Wv = (const float*)d_in[3];
  float* out = (float*)d_out;
  char* ws = (char*)d_ws;

  u16* xb = (u16*)(ws + OFF_XB);
  u16* wqT = (u16*)(ws + OFF_WQT);
  u16* wkT = (u16*)(ws + OFF_WKT);
  u16* wvT = (u16*)(ws + OFF_WVT);
  u16* qb = (u16*)(ws + OFF_Q);
  u16* kb = (u16*)(ws + OFF_K);
  u16* vt = (u16*)(ws + OFF_VT);
  u16* eb = (u16*)(ws + OFF_E);

  const int total = BATCH * SEQ * DIM;
  cast_f32_bf16<<<total / (256 * 8), 256, 0, stream>>>(x, xb);
  transpose_cast_w<<<dim3(32, 32), dim3(32, 8), 0, stream>>>(Wq, wqT);
  transpose_cast_w<<<dim3(32, 32), dim3(32, 8), 0, stream>>>(Wk, wkT);
  transpose_cast_w<<<dim3(32, 32), dim3(32, 8), 0, stream>>>(Wv, wvT);

  // Q = xb·Wq, K = xb·Wk  (M=16384, N=1024, K=1024), 256^2 tiles -> 256 blocks
  gemm256<0><<<dim3(4, 64, 1), 512, 0, stream>>>(xb, 0, DIM, wqT, 0, DIM, qb, 0, DIM,
                                                 DIM, 1.f);
  gemm256<0><<<dim3(4, 64, 1), 512, 0, stream>>>(xb, 0, DIM, wkT, 0, DIM, kb, 0, DIM,
                                                 DIM, 1.f);
  // Vt[b][d][n] = (xb·Wv)[b*2048+n][d]
  gemm256<1><<<dim3(4, 64, 1), 512, 0, stream>>>(xb, 0, DIM, wvT, 0, DIM, vt,
                                                 (size_t)DIM * SEQ, SEQ, DIM, 1.f);
  // E = exp(scale·Q·K^T), causal, bf16, lower 256-tiles only
  gemm256<2><<<dim3(8, 8, BATCH), 512, 0, stream>>>(
      qb, (size_t)SEQ * DIM, DIM, kb, (size_t)SEQ * DIM, DIM, eb, (size_t)SEQ * SEQ, SEQ,
      DIM, 0.03125f);
  // out = (E·V)/rowsum via Vt, K-loop causally limited, heavy tiles first
  gemm_bt<3><<<dim3(8, 16, BATCH), 256, 0, stream>>>(
      eb, (size_t)SEQ * SEQ, SEQ, vt, (size_t)DIM * SEQ, SEQ, out, (size_t)SEQ * DIM, DIM,
      SEQ, 1.f);
}

// Round 2
// 391.324 us; speedup vs baseline: 1.1423x; 1.0666x over previous
//
#include <hip/hip_runtime.h>

// Causal single-head attention, B=8, N=2048, D=1024, fp32 in/out, bf16 MFMA compute.
//
// Pipeline (all on `stream`):
//   1. cast_f32_bf16:      x (fp32) -> xb (bf16)
//   2. transpose_cast_w:   Wq/Wk/Wv (fp32 KxN) -> WT (bf16 NxK)
//   3. gemm256<0>: Q = xb·Wq; K = xb·Wk; gemm256<1>: Vt = (xb·Wv)^T
//   4. gemm256<2>: E = exp(scale·Q·K^T) bf16, causal-masked, lower 256x256 tiles only.
//   5. gemm256<3>: out = (E·V)/rowsum(E), causal K-limit, rowsum from A-fragments.
//
// gemm256: 256x256 tile, 512 thr (8 waves = 2M x 4N), BK=32, 4-deep LDS ring.
// Each K-tile is computed in TWO PHASES (the 8-phase-template granularity: per phase
// {ds-read subtile, stage 2 gload16, barrier, 16 MFMA}), with counted vmcnt(8) once
// per tile (2 full tiles stay in flight across every barrier — T3+T4), XOR-swizzled
// LDS reads via pre-swizzled global source (T2, rule 21), setprio on MFMA (T5).
//
// Phase/WAR safety: a stage issued in phase p overwrites regions last ds_read in
// phase <= p-2; those reads are retired by the readers' operand-waits before their
// phase-(p-1) barrier, which the stager passed before issuing. Tile-t data validity
// at phase reads is established by the vmcnt(8) in tile t-1's phase 1 + barrier.

typedef unsigned short u16;
typedef __bf16 bf16x8 __attribute__((ext_vector_type(8)));
typedef float f32x4 __attribute__((ext_vector_type(4)));
typedef unsigned short u16x8 __attribute__((ext_vector_type(8)));
typedef unsigned short u16x4 __attribute__((ext_vector_type(4)));

static constexpr int BATCH = 8;
static constexpr int SEQ = 2048;
static constexpr int DIM = 1024;

static constexpr size_t SZ_XB = (size_t)BATCH * SEQ * DIM * 2;  // 32 MiB
static constexpr size_t SZ_W  = (size_t)DIM * DIM * 2;          // 2 MiB
static constexpr size_t OFF_XB  = 0;
static constexpr size_t OFF_WQT = OFF_XB + SZ_XB;
static constexpr size_t OFF_WKT = OFF_WQT + SZ_W;
static constexpr size_t OFF_WVT = OFF_WKT + SZ_W;
static constexpr size_t OFF_Q   = OFF_WVT + SZ_W;
static constexpr size_t OFF_K   = OFF_Q + SZ_XB;
static constexpr size_t OFF_VT  = OFF_K + SZ_XB;
static constexpr size_t OFF_E   = OFF_VT + SZ_XB;  // bf16 8x2048x2048 = 64 MiB
// total ~198 MiB

__device__ __forceinline__ u16 f2b(float f) {
  unsigned u = __builtin_bit_cast(unsigned, f);
  u += 0x7fffu + ((u >> 16) & 1u);
  return (u16)(u >> 16);
}

__device__ __forceinline__ void gload16(const u16* g, u16* l) {
  __builtin_amdgcn_global_load_lds((__attribute__((address_space(1))) void*)g,
                                   (__attribute__((address_space(3))) void*)l, 16, 0, 0);
}

#define VWAIT(N) asm volatile("s_waitcnt vmcnt(" #N ")" ::: "memory")

__device__ __forceinline__ void barrier_raw() {
  __builtin_amdgcn_sched_barrier(0);
  __builtin_amdgcn_s_barrier();
  __builtin_amdgcn_sched_barrier(0);
}

__global__ __launch_bounds__(256) void cast_f32_bf16(const float* __restrict__ in,
                                                     u16* __restrict__ out) {
  const size_t i = ((size_t)blockIdx.x * 256 + threadIdx.x) * 8;
  float4 a = *(const float4*)(in + i);
  float4 b = *(const float4*)(in + i + 4);
  u16x8 o;
  o[0] = f2b(a.x); o[1] = f2b(a.y); o[2] = f2b(a.z); o[3] = f2b(a.w);
  o[4] = f2b(b.x); o[5] = f2b(b.y); o[6] = f2b(b.z); o[7] = f2b(b.w);
  *reinterpret_cast<u16x8*>(out + i) = o;
}

__global__ __launch_bounds__(256) void transpose_cast_w(const float* __restrict__ W,
                                                        u16* __restrict__ WT) {
  __shared__ float t[32][33];
  const int k0 = blockIdx.x * 32, n0 = blockIdx.y * 32;
  const int tx = threadIdx.x, ty = threadIdx.y;
#pragma unroll
  for (int dy = 0; dy < 32; dy += 8)
    t[ty + dy][tx] = W[(size_t)(k0 + ty + dy) * DIM + n0 + tx];
  __syncthreads();
#pragma unroll
  for (int dy = 0; dy < 32; dy += 8)
    WT[(size_t)(n0 + ty + dy) * DIM + k0 + tx] = f2b(t[tx][ty + dy]);
}

// ---------------------------------------------------------------------------
// gemm256<MODE>: C = A(bf16 MxK rm) * Bt(bf16 NxK rm)^T, 256x256 tile.
// MODE 0: C bf16 row-major
// MODE 1: C bf16 transposed per batch: C[b][col][n], b=row>>11, n=row&2047 (Vt build)
// MODE 2: C bf16 = exp(acc*scale) causal-masked; lower-triangular tiles only (bx<=by)
// MODE 3: C fp32 = acc / rowsum(A-row); K limited to (by+1)*256; by heavy-first.
//
// LDS swizzle: logical A[256][32] bf16 (64B rows). Read of (row, quad) is 16B at
//   byte ((row*64 + quad*16) ^ (((row>>1)&7)<<4)).
// global_load_lds writes linearly (chunk c -> byte c*16), so the per-lane GLOBAL
// source for chunk c is the inverse image:  P=c>>3, u=(c&7)^(P&7),
//   row = 2P + (u>>2), kchunk = u&3.   (Verified: swz(row,kchunk) == c*16.)
// ---------------------------------------------------------------------------
template <int MODE>
__global__ __launch_bounds__(512, 2) void gemm256(
    const u16* __restrict__ A, size_t sA, int lda,
    const u16* __restrict__ Bt, size_t sB, int ldb,
    void* __restrict__ C, size_t sC, int ldc,
    int Kdim, float scale) {
  const int bx = blockIdx.x, bz = blockIdx.z;
  const int by = (MODE == 3) ? (int)(gridDim.y - 1 - blockIdx.y) : (int)blockIdx.y;
  if (MODE == 2 && bx > by) return;
  const u16* Ab = A + (size_t)bz * sA;
  const u16* Bb = Bt + (size_t)bz * sB;
  const int rowTile = by * 256, colTile = bx * 256;
  int kmax = Kdim;
  if (MODE == 3) {
    int km = (by + 1) * 256;
    if (km < kmax) kmax = km;
  }
  const int NT = kmax >> 5;  // BK=32; NT >= 8 always

  __shared__ __align__(16) u16 lds[4 * 16384];  // 4 stages x (A 16KB + B 16KB) = 128 KiB

  const int tid = threadIdx.x;
  const int w = tid >> 6, l = tid & 63;
  const int wm = w >> 2, wn = w & 3;  // 2 x 4 wave grid; wave owns 128x64 of C
  const int lr = l & 15, quad = l >> 4;

  // staging source pointers (inverse swizzle), chunks c = tid and tid+512
  auto srow = [](int c) { int u = (c & 7) ^ ((c >> 3) & 7); return 2 * (c >> 3) + (u >> 2); };
  auto skq  = [](int c) { int u = (c & 7) ^ ((c >> 3) & 7); return u & 3; };
  const u16* pA0 = Ab + (size_t)(rowTile + srow(tid)) * lda + skq(tid) * 8;
  const u16* pA1 = Ab + (size_t)(rowTile + srow(tid + 512)) * lda + skq(tid + 512) * 8;
  const u16* pB0 = Bb + (size_t)(colTile + srow(tid)) * ldb + skq(tid) * 8;
  const u16* pB1 = Bb + (size_t)(colTile + srow(tid + 512)) * ldb + skq(tid + 512) * 8;

  // swizzled LDS read offsets (u16 units, 16B aligned)
  int offA[8], offB[4];
#pragma unroll
  for (int mi = 0; mi < 8; ++mi) {
    const int row = wm * 128 + mi * 16 + lr;
    offA[mi] = ((row * 64 + quad * 16) ^ (((row >> 1) & 7) << 4)) >> 1;
  }
#pragma unroll
  for (int ni = 0; ni < 4; ++ni) {
    const int row = wn * 64 + ni * 16 + lr;
    offB[ni] = ((row * 64 + quad * 16) ^ (((row >> 1) & 7) << 4)) >> 1;
  }

  f32x4 acc[8][4];
#pragma unroll
  for (int i = 0; i < 8; ++i)
#pragma unroll
    for (int j = 0; j < 4; ++j) acc[i][j] = (f32x4){0.f, 0.f, 0.f, 0.f};
  float rsum[8] = {0.f, 0.f, 0.f, 0.f, 0.f, 0.f, 0.f, 0.f};

#define STAGE_B(tt)                               \
  {                                               \
    u16* sb = &lds[((tt) & 3) * 16384];           \
    const int ko = (tt) * 32;                     \
    gload16(pB0 + ko, sb + 8192 + w * 512);       \
    gload16(pB1 + ko, sb + 12288 + w * 512);      \
  }
#define STAGE_A(tt)                               \
  {                                               \
    u16* sb = &lds[((tt) & 3) * 16384];           \
    const int ko = (tt) * 32;                     \
    gload16(pA0 + ko, sb + w * 512);              \
    gload16(pA1 + ko, sb + 4096 + w * 512);       \
  }

  // prologue: stage tiles 0,1,2 (12 loads/wave); require tile 0 landed, keep 8 in flight
  STAGE_B(0); STAGE_A(0);
  STAGE_B(1); STAGE_A(1);
  STAGE_B(2); STAGE_A(2);
  VWAIT(8);
  barrier_raw();

  for (int t = 0; t < NT; ++t) {
    const u16* As = &lds[(t & 3) * 16384];
    const u16* Bs = As + 8192;
    bf16x8 af[8], bf[4];

    // ---- phase 0: af[0..3] + bf[0..3]; stage B(t+3); MFMA quadrant mh0 ----
#pragma unroll
    for (int mi = 0; mi < 4; ++mi)
      af[mi] = *reinterpret_cast<const bf16x8*>(&As[offA[mi]]);
#pragma unroll
    for (int ni = 0; ni < 4; ++ni)
      bf[ni] = *reinterpret_cast<const bf16x8*>(&Bs[offB[ni]]);
    if (t + 3 < NT) STAGE_B(t + 3);
    barrier_raw();
    if (MODE == 3) {
#pragma unroll
      for (int mi = 0; mi < 4; ++mi) {
        float s = 0.f;
#pragma unroll
        for (int j = 0; j < 8; ++j) s += (float)af[mi][j];
        rsum[mi] += s;
      }
    }
    __builtin_amdgcn_s_setprio(1);
#pragma unroll
    for (int mi = 0; mi < 4; ++mi)
#pragma unroll
      for (int ni = 0; ni < 4; ++ni)
        acc[mi][ni] =
            __builtin_amdgcn_mfma_f32_16x16x32_bf16(af[mi], bf[ni], acc[mi][ni], 0, 0, 0);
    __builtin_amdgcn_s_setprio(0);

    // ---- phase 1: af[4..7]; stage A(t+3); counted vmcnt; MFMA quadrant mh1 ----
#pragma unroll
    for (int mi = 4; mi < 8; ++mi)
      af[mi] = *reinterpret_cast<const bf16x8*>(&As[offA[mi]]);
    if (t + 3 < NT) {
      STAGE_A(t + 3);
      VWAIT(8);   // tiles t+2,t+3 stay in flight; t+1 landed
    } else if (t + 2 < NT) {
      VWAIT(4);   // tile NT-1 stays in flight; t+1 landed
    } else if (t + 1 < NT) {
      VWAIT(0);   // last prefetched tile must land
    }
    barrier_raw();
    if (MODE == 3) {
#pragma unroll
      for (int mi = 4; mi < 8; ++mi) {
        float s = 0.f;
#pragma unroll
        for (int j = 0; j < 8; ++j) s += (float)af[mi][j];
        rsum[mi] += s;
      }
    }
    __builtin_amdgcn_s_setprio(1);
#pragma unroll
    for (int mi = 4; mi < 8; ++mi)
#pragma unroll
      for (int ni = 0; ni < 4; ++ni)
        acc[mi][ni] =
            __builtin_amdgcn_mfma_f32_16x16x32_bf16(af[mi], bf[ni], acc[mi][ni], 0, 0, 0);
    __builtin_amdgcn_s_setprio(0);
  }
#undef STAGE_A
#undef STAGE_B

  if (MODE == 3) {
    // finish row sums: lanes {lr, lr+16, lr+32, lr+48} hold quad-partials
#pragma unroll
    for (int mi = 0; mi < 8; ++mi) {
      rsum[mi] += __shfl_xor(rsum[mi], 16);
      rsum[mi] += __shfl_xor(rsum[mi], 32);
    }
  }

  // C/D layout: col = lane&15, row = (lane>>4)*4 + reg  [m89-verified]
  const int orow0 = rowTile + wm * 128 + quad * 4;
  const int ocol0 = colTile + wn * 64 + lr;
#pragma unroll
  for (int mi = 0; mi < 8; ++mi) {
    float linv[4];
    if (MODE == 3) {
#pragma unroll
      for (int r = 0; r < 4; ++r) linv[r] = 1.f / __shfl(rsum[mi], quad * 4 + r);
    }
#pragma unroll
    for (int ni = 0; ni < 4; ++ni) {
      const int colg = ocol0 + ni * 16;
      if (MODE == 1) {
        const int rowg0 = orow0 + mi * 16;  // multiple of 4; no 2048-boundary cross
        const int bb = rowg0 >> 11, nn = rowg0 & (SEQ - 1);
        u16x4 pk;
#pragma unroll
        for (int r = 0; r < 4; ++r) pk[r] = f2b(acc[mi][ni][r]);
        *reinterpret_cast<u16x4*>(&((u16*)C)[(size_t)bb * sC + (size_t)colg * ldc + nn]) = pk;
      } else {
#pragma unroll
        for (int r = 0; r < 4; ++r) {
          const int rowg = orow0 + mi * 16 + r;
          const float v = acc[mi][ni][r];
          if (MODE == 0) {
            ((u16*)C)[(size_t)bz * sC + (size_t)rowg * ldc + colg] = f2b(v);
          } else if (MODE == 2) {
            const float e = (colg <= rowg) ? __expf(v * scale) : 0.f;
            ((u16*)C)[(size_t)bz * sC + (size_t)rowg * ldc + colg] = f2b(e);
          } else {  // MODE 3
            ((float*)C)[(size_t)bz * sC + (size_t)rowg * ldc + colg] = v * linv[r];
          }
        }
      }
    }
  }
}

extern "C" void kernel_launch(void* const* d_in, const int* in_sizes, int n_in,
                              void* d_out, int out_size, void* d_ws, size_t ws_size,
                              hipStream_t stream) {
  const float* x = (const float*)d_in[0];
  const float* Wq = (const float*)d_in[1];
  const float* Wk = (const float*)d_in[2];
  const float* Wv = (const float*)d_in[3];
  float* out = (float*)d_out;
  char* ws = (char*)d_ws;

  u16* xb = (u16*)(ws + OFF_XB);
  u16* wqT = (u16*)(ws + OFF_WQT);
  u16* wkT = (u16*)(ws + OFF_WKT);
  u16* wvT = (u16*)(ws + OFF_WVT);
  u16* qb = (u16*)(ws + OFF_Q);
  u16* kb = (u16*)(ws + OFF_K);
  u16* vt = (u16*)(ws + OFF_VT);
  u16* eb = (u16*)(ws + OFF_E);

  const int total = BATCH * SEQ * DIM;
  cast_f32_bf16<<<total / (256 * 8), 256, 0, stream>>>(x, xb);
  transpose_cast_w<<<dim3(32, 32), dim3(32, 8), 0, stream>>>(Wq, wqT);
  transpose_cast_w<<<dim3(32, 32), dim3(32, 8), 0, stream>>>(Wk, wkT);
  transpose_cast_w<<<dim3(32, 32), dim3(32, 8), 0, stream>>>(Wv, wvT);

  // Q = xb·Wq, K = xb·Wk  (M=16384, N=1024, K=1024), 256^2 tiles -> 256 blocks
  gemm256<0><<<dim3(4, 64, 1), 512, 0, stream>>>(xb, 0, DIM, wqT, 0, DIM, qb, 0, DIM,
                                                 DIM, 1.f);
  gemm256<0><<<dim3(4, 64, 1), 512, 0, stream>>>(xb, 0, DIM, wkT, 0, DIM, kb, 0, DIM,
                                                 DIM, 1.f);
  // Vt[b][d][n] = (xb·Wv)[b*2048+n][d]
  gemm256<1><<<dim3(4, 64, 1), 512, 0, stream>>>(xb, 0, DIM, wvT, 0, DIM, vt,
                                                 (size_t)DIM * SEQ, SEQ, DIM, 1.f);
  // E = exp(scale·Q·K^T), causal, bf16, lower 256-tiles only
  gemm256<2><<<dim3(8, 8, BATCH), 512, 0, stream>>>(
      qb, (size_t)SEQ * DIM, DIM, kb, (size_t)SEQ * DIM, DIM, eb, (size_t)SEQ * SEQ, SEQ,
      DIM, 0.03125f);
  // out = (E·V)/rowsum via Vt, K-loop causally limited, heavy tiles first
  gemm256<3><<<dim3(4, 8, BATCH), 512, 0, stream>>>(
      eb, (size_t)SEQ * SEQ, SEQ, vt, (size_t)DIM * SEQ, SEQ, out, (size_t)SEQ * DIM, DIM,
      SEQ, 1.f);
}